// Round 4
// baseline (239.058 us; speedup 1.0000x reference)
//
#include <hip/hip_runtime.h>
#include <math.h>

// Match numpy's separate mul/add roundings — no implicit FMA contraction.
// (Explicit __builtin_fmaf below is intentional and unaffected.)
#pragma clang fp contract(off)

#define TPB 256
#define ROWLEN 1024

// Native clang vector type (required by __builtin_nontemporal_store).
typedef float f32x4 __attribute__((ext_vector_type(4)));

// Uniform-value SGPR hoist (value identical across lanes by construction).
static __device__ __forceinline__ float bcast_f32(float v) {
    return __int_as_float(__builtin_amdgcn_readfirstlane(__float_as_int(v)));
}

// ---- DPP wave64 reductions, 2/4 chains INTERLEAVED stage-by-stage ----
// R3 post-mortem: the single serial DPP chain (~100cy, 14 insts) is a
// stall phase all phase-locked waves hit together. Interleaving the two
// rows' chains keeps the latency of ONE chain but doubles the work done
// under it.
__device__ __forceinline__ void wave_max_dpp2(float& a, float& b) {
    const int NI = 0xff800000;                  // -inf bits (fmax identity)
    int va, vb;
#define MSTG(sel, rm, bm) \
    va = __builtin_amdgcn_update_dpp(NI, __float_as_int(a), sel, rm, bm, false); \
    vb = __builtin_amdgcn_update_dpp(NI, __float_as_int(b), sel, rm, bm, false); \
    a = fmaxf(a, __int_as_float(va)); \
    b = fmaxf(b, __int_as_float(vb));
    MSTG(0x111,0xf,0xf) MSTG(0x112,0xf,0xf) MSTG(0x114,0xf,0xf)
    MSTG(0x118,0xf,0xf) MSTG(0x142,0xa,0xf) MSTG(0x143,0xc,0xf)
#undef MSTG
    a = __int_as_float(__builtin_amdgcn_readlane(__float_as_int(a), 63));
    b = __int_as_float(__builtin_amdgcn_readlane(__float_as_int(b), 63));
}

__device__ __forceinline__ void wave_sum_dpp4(unsigned& a, unsigned& b,
                                              unsigned& c, unsigned& d) {
    int v0, v1, v2, v3;
#define SSTG(sel, rm, bm) \
    v0 = __builtin_amdgcn_update_dpp(0, (int)a, sel, rm, bm, false); \
    v1 = __builtin_amdgcn_update_dpp(0, (int)b, sel, rm, bm, false); \
    v2 = __builtin_amdgcn_update_dpp(0, (int)c, sel, rm, bm, false); \
    v3 = __builtin_amdgcn_update_dpp(0, (int)d, sel, rm, bm, false); \
    a += (unsigned)v0; b += (unsigned)v1; c += (unsigned)v2; d += (unsigned)v3;
    SSTG(0x111,0xf,0xf) SSTG(0x112,0xf,0xf) SSTG(0x114,0xf,0xf)
    SSTG(0x118,0xf,0xf) SSTG(0x142,0xa,0xf) SSTG(0x143,0xc,0xf)
#undef SSTG
    a = (unsigned)__builtin_amdgcn_readlane((int)a, 63);
    b = (unsigned)__builtin_amdgcn_readlane((int)b, 63);
    c = (unsigned)__builtin_amdgcn_readlane((int)c, 63);
    d = (unsigned)__builtin_amdgcn_readlane((int)d, 63);
}

// Exact floor(2^32 / s) WITHOUT the ~120-150cy software f64 division.
// s is an exact integer in [3.6e7, 3.8e10] held exactly in f64; the true
// quotient is <= 117. f32 rcp gives a candidate within 3e-5 absolute of
// the true quotient (rel err <= 2.5e-7 from cvt+rcp+mul), so floor() is
// within +-1 of the exact answer; one exact f64-product compare fixes it
// (qf*s < 2^43: exact in f64). Bit-identical to floor(2^32/s).
__device__ __forceinline__ float fac_exact(double s) {
    const float r0 = __builtin_amdgcn_rcpf((float)s);
    float qf = floorf(4294967296.0f * r0);
    const double t = (double)qf * s;               // exact
    if (t > 4294967296.0)           qf -= 1.0f;    // candidate one too high
    else if (t + s <= 4294967296.0) qf += 1.0f;    // candidate one too low
    return qf;
}

// WAVE-per-ROW-PAIR, one-shot grid, zero LDS / zero barriers.
//
// R3 post-mortem: wave-per-row cut instructions (VALUBusy 49->36%) but
// duration stayed ~80us with BW 30% and occupancy 63% — the missing 64%
// of cycles are issue-gaps where ALL resident waves sit in the same
// serial-chain phase simultaneously (phase-locked identical code): DPP
// max chain ~100cy, DPP sum chains ~100cy, f64 division ~120-150cy.
// Fix = intra-wave ILP: each wave processes TWO rows phase-merged, so
// every serial chain carries 2-4 independent interleaved chains, and the
// f64 division is replaced by rcp+exact-fixup (~40cy). Per-row stall
// drops ~2.5-3x. One-shot grid (4096 blocks) restores HW-staggered
// block starts for natural de-phasing.
//
// Numerics: per-element math bit-identical to the verified 224us kernel
// (absmax 4.27e-4 family):
//  - 1/sf, b, c, x0 via double-float Newton (rh+rl ~ 2^-46 rel).
//  - x/sf: double-float multiply + exact-residual FMA ~= CR f32 division.
//  - exp_int: pure f32 mul/add/ldexp/floor — bit-identical to numpy.
//  - Row sum: per-lane u32 over 16 elems <= 16*3.66e7 < 2^30 (exact);
//    lo16 chain < 2^22, hi16 chain < 2^20 (exact u32); total < 2^36
//    exact in f64, order-independent.
//  - factor: fac_exact == floor(2^32/sum) bit-exact (see above).
//  - Epilogue reciprocals f32-rounded: rare +-1 A-quantum flips,
//    3.9e-4 << 1.87e-3 threshold.
__global__ __launch_bounds__(TPB) void qsplit_int_softmax_kernel(
    const float* __restrict__ x,
    const float* __restrict__ scale_p,
    const float* __restrict__ thr_p,
    float* __restrict__ out,
    const int rows)
{
    const int tid  = threadIdx.x;
    const int lane = tid & 63;
    const int wid  = tid >> 6;
    const int gw   = (int)(blockIdx.x << 2) | wid;   // global wave id
    const int rA   = gw << 1;
    if (rA >= rows) return;
    const int  rB   = rA | 1;
    const bool hasB = (rB < rows);                   // wave-uniform

    const float sf  = scale_p[0];   // 0.05f
    const float thr = thr_p[0];     // 0.1f

    // ---- f32 preamble: double-float 1/sf (once per wave) ----
    const float rh = bcast_f32(1.0f / sf);                 // IEEE f32 div
    const float er = __builtin_fmaf(-sf, rh, 1.0f);        // residual
    const float rl = bcast_f32(rh * er);                   // rh+rl ~ 1/sf @2^-46

    // q = a/sf in double-float, then floor (margins: .137/.147/.845)
    #define DF_DIV(a) ({ float _p = (a) * rh; \
                         float _e = __builtin_fmaf((a), rh, -_p); \
                         _p + __builtin_fmaf((a), rl, _e); })
    const float x0f    = bcast_f32(floorf(DF_DIV(-0.69314718f)));    // -14
    const float bfc    = bcast_f32(floorf(DF_DIV(2.7073824f)));      // 54 (c1/c0)
    const float s2     = sf * sf;
    const float r2h    = 1.0f / s2;
    const float r2e    = __builtin_fmaf(-s2, r2h, 1.0f);
    const float r2l    = r2h * r2e;
    const float cq     = __builtin_fmaf(2.7921141f, r2l,
                         2.7921141f * r2h);                          // c2/c0/sf^2
    const float cfc    = bcast_f32(floorf(cq));                      // 1116
    const float clampf = bcast_f32(15.0f * x0f);                     // -210 exact
    const float invx0f = bcast_f32(1.0f / x0f);

    const float osA  = bcast_f32(thr / 255.0f);            // f32 div, as numpy
    const float osB  = bcast_f32(1.0f / 255.0f);
    const float invA = bcast_f32(1.0f / (4294967296.0f * osA)); // <=1ulp vs CR
    const float invB = bcast_f32(1.0f / (4294967296.0f * osB));
    const float thrq = bcast_f32(floorf(thr * 256.0f));    // 25

    // ---- load both rows (4x dwordx4/lane each) ----
    const float* pA = x + (size_t)rA * ROWLEN + ((size_t)lane << 2);
    const float* pB = hasB ? (pA + ROWLEN) : pA;   // safe duplicate if odd tail
    float a[16], b[16];
    #pragma unroll
    for (int g = 0; g < 4; ++g) {
        const f32x4 va = *(const f32x4*)(pA + (g << 8));
        const f32x4 vb = *(const f32x4*)(pB + (g << 8));
        a[4*g+0]=va[0]; a[4*g+1]=va[1]; a[4*g+2]=va[2]; a[4*g+3]=va[3];
        b[4*g+0]=vb[0]; b[4*g+1]=vb[1]; b[4*g+2]=vb[2]; b[4*g+3]=vb[3];
    }

    // ---- x_int = x/sf via double-float (~CR f32 division), both rows ----
    #pragma unroll
    for (int j = 0; j < 16; ++j) {
        { const float xx = a[j];
          const float p  = xx * rh;
          const float e  = __builtin_fmaf(xx, rh, -p);
          a[j] = p + __builtin_fmaf(xx, rl, e); }
        { const float xx = b[j];
          const float p  = xx * rh;
          const float e  = __builtin_fmaf(xx, rh, -p);
          b[j] = p + __builtin_fmaf(xx, rl, e); }
    }

    // ---- row max: local trees + 2 interleaved DPP chains ----
    float mA, mB;
    {
        float t0 = fmaxf(a[0],a[1]),  t1 = fmaxf(a[2],a[3]);
        float t2 = fmaxf(a[4],a[5]),  t3 = fmaxf(a[6],a[7]);
        float t4 = fmaxf(a[8],a[9]),  t5 = fmaxf(a[10],a[11]);
        float t6 = fmaxf(a[12],a[13]),t7 = fmaxf(a[14],a[15]);
        t0 = fmaxf(t0,t1); t2 = fmaxf(t2,t3); t4 = fmaxf(t4,t5); t6 = fmaxf(t6,t7);
        mA = fmaxf(fmaxf(t0,t2), fmaxf(t4,t6));
    }
    {
        float t0 = fmaxf(b[0],b[1]),  t1 = fmaxf(b[2],b[3]);
        float t2 = fmaxf(b[4],b[5]),  t3 = fmaxf(b[6],b[7]);
        float t4 = fmaxf(b[8],b[9]),  t5 = fmaxf(b[10],b[11]);
        float t6 = fmaxf(b[12],b[13]),t7 = fmaxf(b[14],b[15]);
        t0 = fmaxf(t0,t1); t2 = fmaxf(t2,t3); t4 = fmaxf(t4,t5); t6 = fmaxf(t6,t7);
        mB = fmaxf(fmaxf(t0,t2), fmaxf(t4,t6));
    }
    wave_max_dpp2(mA, mB);

    // ---- integer exp (f32/int, bit-matching numpy), both rows ----
    unsigned usA = 0, usB = 0;    // each <= 16*3.66e7 < 2^30: exact
    #pragma unroll
    for (int j = 0; j < 16; ++j) {
        { float v = a[j] - mA;
          v = fmaxf(v, clampf);
          const float qf = floorf(v * invx0f);
          const int   qi = (int)qf;
          const float rr = v - x0f * qf;
          const float t  = rr + bfc;
          const float z  = rr * t + cfc;          // two roundings (contract off)
          float ei = floorf(ldexpf(z, 15 - qi));
          ei = fmaxf(ei, 0.0f);
          a[j] = ei; usA += (unsigned)ei; }
        { float v = b[j] - mB;
          v = fmaxf(v, clampf);
          const float qf = floorf(v * invx0f);
          const int   qi = (int)qf;
          const float rr = v - x0f * qf;
          const float t  = rr + bfc;
          const float z  = rr * t + cfc;
          float ei = floorf(ldexpf(z, 15 - qi));
          ei = fmaxf(ei, 0.0f);
          b[j] = ei; usB += (unsigned)ei; }
    }

    // ---- row sums: 4 interleaved DPP chains (all exact u32) ----
    unsigned loA = usA & 0xFFFFu, hiA = usA >> 16;
    unsigned loB = usB & 0xFFFFu, hiB = usB >> 16;
    wave_sum_dpp4(loA, hiA, loB, hiB);
    const double sA = (double)(((unsigned long long)hiA << 16) + loA); // exact int
    const double sB = (double)(((unsigned long long)hiB << 16) + loB);

    // ---- row-uniform epilogue constants (both rows interleave) ----
    const float facA = bcast_f32(fac_exact(sA));
    const float facB = bcast_f32(fac_exact(sB));
    const float athA = bcast_f32((float)(((double)thrq * sA) * (1.0 / 256.0)));
    const float athB = bcast_f32((float)(((double)thrq * sB) * (1.0 / 256.0)));

    // ---- quantize + nontemporal store, row A then row B ----
    float* poA = out + (size_t)rA * ROWLEN + ((size_t)lane << 2);
    #pragma unroll
    for (int g = 0; g < 4; ++g) {
        f32x4 o;
        #pragma unroll
        for (int jj = 0; jj < 4; ++jj) {
            const float ei  = a[4*g+jj];
            const bool  isA = (ei <= athA);
            const float t1_ = ei * facA;                // bit-matches numpy
            const float t2_ = t1_ * (isA ? invA : invB);
            float si = floorf(t2_);
            si = fminf(si, isA ? 3.0e38f : 255.0f);     // cap only B path
            o[jj] = si * (isA ? osA : osB);
        }
        __builtin_nontemporal_store(o, (f32x4*)(poA + (g << 8)));
    }
    if (hasB) {
        float* poB = poA + ROWLEN;
        #pragma unroll
        for (int g = 0; g < 4; ++g) {
            f32x4 o;
            #pragma unroll
            for (int jj = 0; jj < 4; ++jj) {
                const float ei  = b[4*g+jj];
                const bool  isA = (ei <= athB);
                const float t1_ = ei * facB;
                const float t2_ = t1_ * (isA ? invA : invB);
                float si = floorf(t2_);
                si = fminf(si, isA ? 3.0e38f : 255.0f);
                o[jj] = si * (isA ? osA : osB);
            }
            __builtin_nontemporal_store(o, (f32x4*)(poB + (g << 8)));
        }
    }
}

extern "C" void kernel_launch(void* const* d_in, const int* in_sizes, int n_in,
                              void* d_out, int out_size, void* d_ws, size_t ws_size,
                              hipStream_t stream) {
    const float* x     = (const float*)d_in[0];
    const float* scale = (const float*)d_in[1];
    const float* thr   = (const float*)d_in[2];
    float* out = (float*)d_out;

    const int total = in_sizes[0];        // 2*16*1024*1024
    const int rows  = total / ROWLEN;     // 32768 rows

    const int waves  = (rows + 1) / 2;    // one wave per row-pair
    const int blocks = (waves + 3) / 4;   // 4 waves per block -> 4096 blocks

    qsplit_int_softmax_kernel<<<dim3(blocks), dim3(TPB), 0, stream>>>(
        x, scale, thr, out, rows);
}

// Round 5
// 236.793 us; speedup vs baseline: 1.0096x; 1.0096x over previous
//
#include <hip/hip_runtime.h>
#include <math.h>

// Match numpy's separate mul/add roundings — no implicit FMA contraction.
// (Explicit __builtin_fmaf below is intentional and unaffected.)
#pragma clang fp contract(off)

#define TPB 256
#define ROWLEN 1024

typedef float f32x4 __attribute__((ext_vector_type(4)));

// Uniform-value SGPR hoist (value identical across lanes by construction).
static __device__ __forceinline__ float bcast_f32(float v) {
    return __int_as_float(__builtin_amdgcn_readfirstlane(__float_as_int(v)));
}

// ---- DPP wave64 reductions, 2/4 chains INTERLEAVED stage-by-stage ----
__device__ __forceinline__ void wave_max_dpp2(float& a, float& b) {
    const int NI = 0xff800000;                  // -inf bits (fmax identity)
    int va, vb;
#define MSTG(sel, rm, bm) \
    va = __builtin_amdgcn_update_dpp(NI, __float_as_int(a), sel, rm, bm, false); \
    vb = __builtin_amdgcn_update_dpp(NI, __float_as_int(b), sel, rm, bm, false); \
    a = fmaxf(a, __int_as_float(va)); \
    b = fmaxf(b, __int_as_float(vb));
    MSTG(0x111,0xf,0xf) MSTG(0x112,0xf,0xf) MSTG(0x114,0xf,0xf)
    MSTG(0x118,0xf,0xf) MSTG(0x142,0xa,0xf) MSTG(0x143,0xc,0xf)
#undef MSTG
    a = __int_as_float(__builtin_amdgcn_readlane(__float_as_int(a), 63));
    b = __int_as_float(__builtin_amdgcn_readlane(__float_as_int(b), 63));
}

__device__ __forceinline__ void wave_sum_dpp4(unsigned& a, unsigned& b,
                                              unsigned& c, unsigned& d) {
    int v0, v1, v2, v3;
#define SSTG(sel, rm, bm) \
    v0 = __builtin_amdgcn_update_dpp(0, (int)a, sel, rm, bm, false); \
    v1 = __builtin_amdgcn_update_dpp(0, (int)b, sel, rm, bm, false); \
    v2 = __builtin_amdgcn_update_dpp(0, (int)c, sel, rm, bm, false); \
    v3 = __builtin_amdgcn_update_dpp(0, (int)d, sel, rm, bm, false); \
    a += (unsigned)v0; b += (unsigned)v1; c += (unsigned)v2; d += (unsigned)v3;
    SSTG(0x111,0xf,0xf) SSTG(0x112,0xf,0xf) SSTG(0x114,0xf,0xf)
    SSTG(0x118,0xf,0xf) SSTG(0x142,0xa,0xf) SSTG(0x143,0xc,0xf)
#undef SSTG
    a = (unsigned)__builtin_amdgcn_readlane((int)a, 63);
    b = (unsigned)__builtin_amdgcn_readlane((int)b, 63);
    c = (unsigned)__builtin_amdgcn_readlane((int)c, 63);
    d = (unsigned)__builtin_amdgcn_readlane((int)d, 63);
}

// Exact floor(2^32 / s) without the software f64 division.
// s is an exact integer in [3.6e7, 3.8e10] held exactly in f64; the true
// quotient is <= 117. f32 rcp gives a candidate within 3e-5 absolute of
// the true quotient, so floor() is within +-1 of exact; one exact
// f64-product compare fixes it (qf*s < 2^43: exact). Bit-identical to
// floor(2^32/s).
__device__ __forceinline__ float fac_exact(double s) {
    const float r0 = __builtin_amdgcn_rcpf((float)s);
    float qf = floorf(4294967296.0f * r0);
    const double t = (double)qf * s;               // exact
    if (t > 4294967296.0)           qf -= 1.0f;    // candidate one too high
    else if (t + s <= 4294967296.0) qf += 1.0f;    // candidate one too low
    return qf;
}

// WAVE-per-ROW-PAIR, one-shot grid, zero LDS / zero barriers.
// PLAIN stores (NT removed).
//
// R4 post-mortem: three structurally different kernels (block-per-row
// persistent, wave-per-row persistent, wave-per-pair one-shot) all pin
// at the SAME wall: output write stream = 131072KB / ~82us ~= 1.6 TB/s,
// spanning the whole kernel (VALUBusy 36% = 30us of VALU hiding under a
// write-limited envelope). The harness fill writes 524MB at 6.75 TB/s
// with plain stores on the same box. The one constant across all our
// kernels that the fill lacks: __builtin_nontemporal_store. Theory: the
// NT/no-allocate flag bypasses L2 write-combining and caps the write
// path ~4x below peak. This round changes ONLY that: NT -> plain
// global_store_dwordx4. Everything else is R4 verbatim.
//
// Numerics: per-element math bit-identical to the verified kernel
// (absmax 4.27e-4 family):
//  - 1/sf, b, c, x0 via double-float Newton (rh+rl ~ 2^-46 rel).
//  - x/sf: double-float multiply + exact-residual FMA ~= CR f32 division.
//  - exp_int: pure f32 mul/add/ldexp/floor — bit-identical to numpy.
//  - Row sum: per-lane u32 over 16 elems < 2^30 (exact); lo16 chain
//    < 2^22, hi16 chain < 2^20 (exact u32); total < 2^36 exact in f64,
//    order-independent.
//  - factor: fac_exact == floor(2^32/sum) bit-exact.
//  - Epilogue reciprocals f32-rounded: rare +-1 A-quantum flips,
//    3.9e-4 << 1.87e-3 threshold.
__global__ __launch_bounds__(TPB) void qsplit_int_softmax_kernel(
    const float* __restrict__ x,
    const float* __restrict__ scale_p,
    const float* __restrict__ thr_p,
    float* __restrict__ out,
    const int rows)
{
    const int tid  = threadIdx.x;
    const int lane = tid & 63;
    const int wid  = tid >> 6;
    const int gw   = (int)(blockIdx.x << 2) | wid;   // global wave id
    const int rA   = gw << 1;
    if (rA >= rows) return;
    const int  rB   = rA | 1;
    const bool hasB = (rB < rows);                   // wave-uniform

    const float sf  = scale_p[0];   // 0.05f
    const float thr = thr_p[0];     // 0.1f

    // ---- f32 preamble: double-float 1/sf (once per wave) ----
    const float rh = bcast_f32(1.0f / sf);                 // IEEE f32 div
    const float er = __builtin_fmaf(-sf, rh, 1.0f);        // residual
    const float rl = bcast_f32(rh * er);                   // rh+rl ~ 1/sf @2^-46

    // q = a/sf in double-float, then floor (margins: .137/.147/.845)
    #define DF_DIV(a) ({ float _p = (a) * rh; \
                         float _e = __builtin_fmaf((a), rh, -_p); \
                         _p + __builtin_fmaf((a), rl, _e); })
    const float x0f    = bcast_f32(floorf(DF_DIV(-0.69314718f)));    // -14
    const float bfc    = bcast_f32(floorf(DF_DIV(2.7073824f)));      // 54 (c1/c0)
    const float s2     = sf * sf;
    const float r2h    = 1.0f / s2;
    const float r2e    = __builtin_fmaf(-s2, r2h, 1.0f);
    const float r2l    = r2h * r2e;
    const float cq     = __builtin_fmaf(2.7921141f, r2l,
                         2.7921141f * r2h);                          // c2/c0/sf^2
    const float cfc    = bcast_f32(floorf(cq));                      // 1116
    const float clampf = bcast_f32(15.0f * x0f);                     // -210 exact
    const float invx0f = bcast_f32(1.0f / x0f);

    const float osA  = bcast_f32(thr / 255.0f);            // f32 div, as numpy
    const float osB  = bcast_f32(1.0f / 255.0f);
    const float invA = bcast_f32(1.0f / (4294967296.0f * osA)); // <=1ulp vs CR
    const float invB = bcast_f32(1.0f / (4294967296.0f * osB));
    const float thrq = bcast_f32(floorf(thr * 256.0f));    // 25

    // ---- load both rows (4x dwordx4/lane each) ----
    const float* pA = x + (size_t)rA * ROWLEN + ((size_t)lane << 2);
    const float* pB = hasB ? (pA + ROWLEN) : pA;   // safe duplicate if odd tail
    float a[16], b[16];
    #pragma unroll
    for (int g = 0; g < 4; ++g) {
        const f32x4 va = *(const f32x4*)(pA + (g << 8));
        const f32x4 vb = *(const f32x4*)(pB + (g << 8));
        a[4*g+0]=va[0]; a[4*g+1]=va[1]; a[4*g+2]=va[2]; a[4*g+3]=va[3];
        b[4*g+0]=vb[0]; b[4*g+1]=vb[1]; b[4*g+2]=vb[2]; b[4*g+3]=vb[3];
    }

    // ---- x_int = x/sf via double-float (~CR f32 division), both rows ----
    #pragma unroll
    for (int j = 0; j < 16; ++j) {
        { const float xx = a[j];
          const float p  = xx * rh;
          const float e  = __builtin_fmaf(xx, rh, -p);
          a[j] = p + __builtin_fmaf(xx, rl, e); }
        { const float xx = b[j];
          const float p  = xx * rh;
          const float e  = __builtin_fmaf(xx, rh, -p);
          b[j] = p + __builtin_fmaf(xx, rl, e); }
    }

    // ---- row max: local trees + 2 interleaved DPP chains ----
    float mA, mB;
    {
        float t0 = fmaxf(a[0],a[1]),  t1 = fmaxf(a[2],a[3]);
        float t2 = fmaxf(a[4],a[5]),  t3 = fmaxf(a[6],a[7]);
        float t4 = fmaxf(a[8],a[9]),  t5 = fmaxf(a[10],a[11]);
        float t6 = fmaxf(a[12],a[13]),t7 = fmaxf(a[14],a[15]);
        t0 = fmaxf(t0,t1); t2 = fmaxf(t2,t3); t4 = fmaxf(t4,t5); t6 = fmaxf(t6,t7);
        mA = fmaxf(fmaxf(t0,t2), fmaxf(t4,t6));
    }
    {
        float t0 = fmaxf(b[0],b[1]),  t1 = fmaxf(b[2],b[3]);
        float t2 = fmaxf(b[4],b[5]),  t3 = fmaxf(b[6],b[7]);
        float t4 = fmaxf(b[8],b[9]),  t5 = fmaxf(b[10],b[11]);
        float t6 = fmaxf(b[12],b[13]),t7 = fmaxf(b[14],b[15]);
        t0 = fmaxf(t0,t1); t2 = fmaxf(t2,t3); t4 = fmaxf(t4,t5); t6 = fmaxf(t6,t7);
        mB = fmaxf(fmaxf(t0,t2), fmaxf(t4,t6));
    }
    wave_max_dpp2(mA, mB);

    // ---- integer exp (f32/int, bit-matching numpy), both rows ----
    unsigned usA = 0, usB = 0;    // each <= 16*3.66e7 < 2^30: exact
    #pragma unroll
    for (int j = 0; j < 16; ++j) {
        { float v = a[j] - mA;
          v = fmaxf(v, clampf);
          const float qf = floorf(v * invx0f);
          const int   qi = (int)qf;
          const float rr = v - x0f * qf;
          const float t  = rr + bfc;
          const float z  = rr * t + cfc;          // two roundings (contract off)
          float ei = floorf(ldexpf(z, 15 - qi));
          ei = fmaxf(ei, 0.0f);
          a[j] = ei; usA += (unsigned)ei; }
        { float v = b[j] - mB;
          v = fmaxf(v, clampf);
          const float qf = floorf(v * invx0f);
          const int   qi = (int)qf;
          const float rr = v - x0f * qf;
          const float t  = rr + bfc;
          const float z  = rr * t + cfc;
          float ei = floorf(ldexpf(z, 15 - qi));
          ei = fmaxf(ei, 0.0f);
          b[j] = ei; usB += (unsigned)ei; }
    }

    // ---- row sums: 4 interleaved DPP chains (all exact u32) ----
    unsigned loA = usA & 0xFFFFu, hiA = usA >> 16;
    unsigned loB = usB & 0xFFFFu, hiB = usB >> 16;
    wave_sum_dpp4(loA, hiA, loB, hiB);
    const double sA = (double)(((unsigned long long)hiA << 16) + loA); // exact int
    const double sB = (double)(((unsigned long long)hiB << 16) + loB);

    // ---- row-uniform epilogue constants (both rows interleave) ----
    const float facA = bcast_f32(fac_exact(sA));
    const float facB = bcast_f32(fac_exact(sB));
    const float athA = bcast_f32((float)(((double)thrq * sA) * (1.0 / 256.0)));
    const float athB = bcast_f32((float)(((double)thrq * sB) * (1.0 / 256.0)));

    // ---- quantize + PLAIN store (the experiment: NT removed) ----
    float* poA = out + (size_t)rA * ROWLEN + ((size_t)lane << 2);
    #pragma unroll
    for (int g = 0; g < 4; ++g) {
        f32x4 o;
        #pragma unroll
        for (int jj = 0; jj < 4; ++jj) {
            const float ei  = a[4*g+jj];
            const bool  isA = (ei <= athA);
            const float t1_ = ei * facA;                // bit-matches numpy
            const float t2_ = t1_ * (isA ? invA : invB);
            float si = floorf(t2_);
            si = fminf(si, isA ? 3.0e38f : 255.0f);     // cap only B path
            o[jj] = si * (isA ? osA : osB);
        }
        *(f32x4*)(poA + (g << 8)) = o;
    }
    if (hasB) {
        float* poB = poA + ROWLEN;
        #pragma unroll
        for (int g = 0; g < 4; ++g) {
            f32x4 o;
            #pragma unroll
            for (int jj = 0; jj < 4; ++jj) {
                const float ei  = b[4*g+jj];
                const bool  isA = (ei <= athB);
                const float t1_ = ei * facB;
                const float t2_ = t1_ * (isA ? invA : invB);
                float si = floorf(t2_);
                si = fminf(si, isA ? 3.0e38f : 255.0f);
                o[jj] = si * (isA ? osA : osB);
            }
            *(f32x4*)(poB + (g << 8)) = o;
        }
    }
}

extern "C" void kernel_launch(void* const* d_in, const int* in_sizes, int n_in,
                              void* d_out, int out_size, void* d_ws, size_t ws_size,
                              hipStream_t stream) {
    const float* x     = (const float*)d_in[0];
    const float* scale = (const float*)d_in[1];
    const float* thr   = (const float*)d_in[2];
    float* out = (float*)d_out;

    const int total = in_sizes[0];        // 2*16*1024*1024
    const int rows  = total / ROWLEN;     // 32768 rows

    const int waves  = (rows + 1) / 2;    // one wave per row-pair
    const int blocks = (waves + 3) / 4;   // 4 waves per block -> 4096 blocks

    qsplit_int_softmax_kernel<<<dim3(blocks), dim3(TPB), 0, stream>>>(
        x, scale, thr, out, rows);
}

// Round 6
// 233.782 us; speedup vs baseline: 1.0226x; 1.0129x over previous
//
#include <hip/hip_runtime.h>
#include <math.h>

// Match numpy's separate mul/add roundings — no implicit FMA contraction.
// (Explicit __builtin_fmaf below is intentional and unaffected.)
#pragma clang fp contract(off)

#define TPB 256
#define ROWLEN 1024

typedef float f32x4 __attribute__((ext_vector_type(4)));

// Uniform-value SGPR hoist (value identical across lanes by construction).
static __device__ __forceinline__ float bcast_f32(float v) {
    return __int_as_float(__builtin_amdgcn_readfirstlane(__float_as_int(v)));
}

// ---- DPP wave64 reductions (VALU-only; no LDS, no barriers) ----
__device__ __forceinline__ float wave_max_dpp(float m) {
    const int NI = 0xff800000;                  // -inf bits (fmax identity)
    int v;
    v = __builtin_amdgcn_update_dpp(NI, __float_as_int(m), 0x111, 0xf, 0xf, false);
    m = fmaxf(m, __int_as_float(v));
    v = __builtin_amdgcn_update_dpp(NI, __float_as_int(m), 0x112, 0xf, 0xf, false);
    m = fmaxf(m, __int_as_float(v));
    v = __builtin_amdgcn_update_dpp(NI, __float_as_int(m), 0x114, 0xf, 0xf, false);
    m = fmaxf(m, __int_as_float(v));
    v = __builtin_amdgcn_update_dpp(NI, __float_as_int(m), 0x118, 0xf, 0xf, false);
    m = fmaxf(m, __int_as_float(v));
    v = __builtin_amdgcn_update_dpp(NI, __float_as_int(m), 0x142, 0xa, 0xf, false);
    m = fmaxf(m, __int_as_float(v));
    v = __builtin_amdgcn_update_dpp(NI, __float_as_int(m), 0x143, 0xc, 0xf, false);
    m = fmaxf(m, __int_as_float(v));
    return __int_as_float(__builtin_amdgcn_readlane(__float_as_int(m), 63));
}

// lo16/hi16 sum chains interleaved (2 independent chains under one latency).
__device__ __forceinline__ void wave_sum_dpp2(unsigned& a, unsigned& b) {
    int v0, v1;
#define SSTG(sel, rm, bm) \
    v0 = __builtin_amdgcn_update_dpp(0, (int)a, sel, rm, bm, false); \
    v1 = __builtin_amdgcn_update_dpp(0, (int)b, sel, rm, bm, false); \
    a += (unsigned)v0; b += (unsigned)v1;
    SSTG(0x111,0xf,0xf) SSTG(0x112,0xf,0xf) SSTG(0x114,0xf,0xf)
    SSTG(0x118,0xf,0xf) SSTG(0x142,0xa,0xf) SSTG(0x143,0xc,0xf)
#undef SSTG
    a = (unsigned)__builtin_amdgcn_readlane((int)a, 63);
    b = (unsigned)__builtin_amdgcn_readlane((int)b, 63);
}

// Exact floor(2^32 / s) without the software f64 division.
// s is an exact integer in [3.6e7, 3.8e10] held exactly in f64; the true
// quotient is <= 117. f32 rcp gives a candidate within 3e-5 absolute of
// the true quotient, so floor() is within +-1 of exact; one exact
// f64-product compare fixes it (qf*s < 2^43: exact). Bit-identical to
// floor(2^32/s).
__device__ __forceinline__ float fac_exact(double s) {
    const float r0 = __builtin_amdgcn_rcpf((float)s);
    float qf = floorf(4294967296.0f * r0);
    const double t = (double)qf * s;               // exact
    if (t > 4294967296.0)           qf -= 1.0f;    // candidate one too high
    else if (t + s <= 4294967296.0) qf += 1.0f;    // candidate one too low
    return qf;
}

// WAVE-per-ROW, ONE-SHOT grid, zero LDS / zero barriers, NO SPILL.
//
// R5 post-mortem: the session's regression tracks register pressure.
// R4/R5 report VGPR_Count=28 while holding 32 live floats (a[16]+b[16])
// across the reductions -> scratch SPILL (private-mem round trips:
// latency invisible in FETCH/VALU counters). R3's (256,8) 64-VGPR cap
// with 32 live floats was likewise compromised. The clean kernels
// (baseline, R2: 20 VGPR, 4 elems/thread) sit at ~76-80us; spilled ones
// 84-86us. This round: keep R3's instruction-count win (wave-per-row
// amortization: VALUBusy 49->36%) but with a SINGLE a[16] array
// (~32-48 VGPRs incl. temps: fits without spill), one-shot 8192-block
// grid (best-measured dispatch mode), no barriers, no LDS, no prefetch
// (one-shot blocks overlap via HW dispatch instead).
//
// Numerics: per-element math bit-identical to the verified kernel
// (absmax 4.27e-4 family):
//  - 1/sf, b, c, x0 via double-float Newton (rh+rl ~ 2^-46 rel).
//  - x/sf: double-float multiply + exact-residual FMA ~= CR f32 division.
//  - exp_int: pure f32 mul/add/ldexp/floor — bit-identical to numpy.
//  - Row sum: per-lane u32 over 16 elems < 2^30 (exact); lo16 chain
//    < 2^22, hi16 chain < 2^20 (exact u32); total < 2^36 exact in f64,
//    order-independent.
//  - factor: fac_exact == floor(2^32/sum) bit-exact.
//  - Epilogue reciprocals f32-rounded: rare +-1 A-quantum flips,
//    3.9e-4 << 1.87e-3 threshold.
__global__ __launch_bounds__(TPB, 8) void qsplit_int_softmax_kernel(
    const float* __restrict__ x,
    const float* __restrict__ scale_p,
    const float* __restrict__ thr_p,
    float* __restrict__ out,
    const int rows)
{
    const int tid  = threadIdx.x;
    const int lane = tid & 63;
    const int wid  = tid >> 6;
    const int r    = (int)(blockIdx.x << 2) | wid;   // this wave's row
    if (r >= rows) return;

    const float sf  = scale_p[0];   // 0.05f
    const float thr = thr_p[0];     // 0.1f

    // ---- f32 preamble: double-float 1/sf (SGPR-hoisted constants) ----
    const float rh = bcast_f32(1.0f / sf);                 // IEEE f32 div
    const float er = __builtin_fmaf(-sf, rh, 1.0f);        // residual
    const float rl = bcast_f32(rh * er);                   // rh+rl ~ 1/sf @2^-46

    // q = a/sf in double-float, then floor (margins: .137/.147/.845)
    #define DF_DIV(a) ({ float _p = (a) * rh; \
                         float _e = __builtin_fmaf((a), rh, -_p); \
                         _p + __builtin_fmaf((a), rl, _e); })
    const float x0f    = bcast_f32(floorf(DF_DIV(-0.69314718f)));    // -14
    const float bfc    = bcast_f32(floorf(DF_DIV(2.7073824f)));      // 54 (c1/c0)
    const float s2     = sf * sf;
    const float r2h    = 1.0f / s2;
    const float r2e    = __builtin_fmaf(-s2, r2h, 1.0f);
    const float r2l    = r2h * r2e;
    const float cq     = __builtin_fmaf(2.7921141f, r2l,
                         2.7921141f * r2h);                          // c2/c0/sf^2
    const float cfc    = bcast_f32(floorf(cq));                      // 1116
    const float clampf = bcast_f32(15.0f * x0f);                     // -210 exact
    const float invx0f = bcast_f32(1.0f / x0f);

    const float osA  = bcast_f32(thr / 255.0f);            // f32 div, as numpy
    const float osB  = bcast_f32(1.0f / 255.0f);
    const float invA = bcast_f32(1.0f / (4294967296.0f * osA)); // <=1ulp vs CR
    const float invB = bcast_f32(1.0f / (4294967296.0f * osB));
    const float thrq = bcast_f32(floorf(thr * 256.0f));    // 25

    // ---- load row (4x dwordx4/lane; imm offsets 0/1/2/3 KB) ----
    const float* px = x + (size_t)r * ROWLEN + ((size_t)lane << 2);
    float a[16];
    #pragma unroll
    for (int g = 0; g < 4; ++g) {
        const f32x4 v = *(const f32x4*)(px + (g << 8));
        a[4*g+0] = v[0]; a[4*g+1] = v[1];
        a[4*g+2] = v[2]; a[4*g+3] = v[3];
    }

    // ---- x_int = x/sf via double-float (~CR f32 division), in place ----
    #pragma unroll
    for (int j = 0; j < 16; ++j) {
        const float xx = a[j];
        const float p  = xx * rh;
        const float e  = __builtin_fmaf(xx, rh, -p);   // exact residual
        a[j] = p + __builtin_fmaf(xx, rl, e);
    }

    // ---- row max: local tree (15 ops, depth 4) + one DPP chain ----
    float t0 = fmaxf(a[0],a[1]),  t1 = fmaxf(a[2],a[3]);
    float t2 = fmaxf(a[4],a[5]),  t3 = fmaxf(a[6],a[7]);
    float t4 = fmaxf(a[8],a[9]),  t5 = fmaxf(a[10],a[11]);
    float t6 = fmaxf(a[12],a[13]),t7 = fmaxf(a[14],a[15]);
    t0 = fmaxf(t0,t1); t2 = fmaxf(t2,t3); t4 = fmaxf(t4,t5); t6 = fmaxf(t6,t7);
    const float m = wave_max_dpp(fmaxf(fmaxf(t0,t2), fmaxf(t4,t6)));

    // ---- integer exp (f32/int, bit-matching numpy), in place ----
    unsigned usum = 0;    // <= 16 * 3.66e7 < 2^30: exact
    #pragma unroll
    for (int j = 0; j < 16; ++j) {
        float v = a[j] - m;                   // exact f32 sub
        v = fmaxf(v, clampf);                 // >= -210
        const float qf = floorf(v * invx0f);  // in [0,15]; flips benign
        const int   qi = (int)qf;
        const float rr = v - x0f * qf;        // exact in f32
        const float t  = rr + bfc;
        const float z  = rr * t + cfc;        // two roundings (contract off)
        float ei = floorf(ldexpf(z, 15 - qi)); // pow2 scale exact
        ei = fmaxf(ei, 0.0f);
        a[j] = ei;
        usum += (unsigned)ei;
    }

    // ---- row sum: lo/hi u32 DPP chains (exact, interleaved) ----
    unsigned lo = usum & 0xFFFFu, hi = usum >> 16;   // < 2^22 / < 2^20
    wave_sum_dpp2(lo, hi);
    const double s = (double)(((unsigned long long)hi << 16) + lo);  // exact int

    // ---- row-uniform epilogue constants ----
    const float fac_f = bcast_f32(fac_exact(s));                     // exact int
    const float ath_f = bcast_f32((float)(((double)thrq * s) * (1.0 / 256.0)));

    // ---- quantize + nontemporal store ----
    float* po = out + (size_t)r * ROWLEN + ((size_t)lane << 2);
    #pragma unroll
    for (int g = 0; g < 4; ++g) {
        f32x4 o;
        #pragma unroll
        for (int jj = 0; jj < 4; ++jj) {
            const float ei  = a[4*g+jj];
            const bool  isA = (ei <= ath_f);
            const float t1_ = ei * fac_f;               // bit-matches numpy
            const float t2_ = t1_ * (isA ? invA : invB); // ~f32 division
            float si = floorf(t2_);
            si = fminf(si, isA ? 3.0e38f : 255.0f);     // cap only B path
            o[jj] = si * (isA ? osA : osB);
        }
        __builtin_nontemporal_store(o, (f32x4*)(po + (g << 8)));
    }
}

extern "C" void kernel_launch(void* const* d_in, const int* in_sizes, int n_in,
                              void* d_out, int out_size, void* d_ws, size_t ws_size,
                              hipStream_t stream) {
    const float* x     = (const float*)d_in[0];
    const float* scale = (const float*)d_in[1];
    const float* thr   = (const float*)d_in[2];
    float* out = (float*)d_out;

    const int total = in_sizes[0];        // 2*16*1024*1024
    const int rows  = total / ROWLEN;     // 32768 rows

    const int blocks = (rows + 3) / 4;    // 4 row-waves per block -> 8192 blocks

    qsplit_int_softmax_kernel<<<dim3(blocks), dim3(TPB), 0, stream>>>(
        x, scale, thr, out, rows);
}